// Round 3
// baseline (1217.419 us; speedup 1.0000x reference)
//
#include <hip/hip_runtime.h>
#include <math.h>

#define NN 20000   // nodes
#define NE 100000  // edges per edge set
#define DD 128     // hidden
#define FF 16      // node features
#define NL 12      // layers
#define NG 64      // graphs

typedef unsigned short u16;
typedef short short8 __attribute__((ext_vector_type(8)));
typedef float f32x4 __attribute__((ext_vector_type(4)));

__device__ __forceinline__ float silu_f(float x) { return x / (1.0f + __expf(-x)); }

// round-to-nearest-even f32 -> bf16
__device__ __forceinline__ u16 f2b(float f) {
    union { float f; unsigned int u; } v; v.f = f;
    unsigned int r = v.u + 0x7fffu + ((v.u >> 16) & 1u);
    return (u16)(r >> 16);
}
__device__ __forceinline__ float b2f(u16 b) {
    union { unsigned int u; float f; } v; v.u = ((unsigned int)b) << 16;
    return v.f;
}

// ---- weight prep: fp32 [L][Ksrc][128] -> bf16 transposed [L][128][Kdst] ----
__global__ void wprep_kernel(const float* __restrict__ src, u16* __restrict__ dst,
                             int Ksrc, int Kdst) {
    int gid = blockIdx.x * 256 + threadIdx.x;
    int total = NL * 128 * Kdst;
    if (gid >= total) return;
    int k = gid % Kdst;
    int c = (gid / Kdst) & 127;
    int l = gid / (Kdst * 128);
    dst[gid] = f2b(src[((size_t)l * Ksrc + k) * 128 + c]);
}

// ---- embedding ----
__global__ void embed_kernel(const float* __restrict__ x, const float* __restrict__ W,
                             const float* __restrict__ b, float* __restrict__ h,
                             u16* __restrict__ hb) {
    int gid = blockIdx.x * 256 + threadIdx.x;
    if (gid >= NN * DD) return;
    int n = gid >> 7, c = gid & 127;
    float s = b[c];
    const float* xr = x + n * FF;
#pragma unroll
    for (int k = 0; k < FF; ++k) s += xr[k] * W[k * DD + c];
    h[gid] = s;
    hb[gid] = f2b(s);
}

// ================== CSR build (once per call, per edge set) ==================
__global__ void hist_kernel(const int* __restrict__ eidx, int* __restrict__ cnt) {
    int e = blockIdx.x * 256 + threadIdx.x;
    if (e >= NE) return;
    atomicAdd(&cnt[eidx[NE + e]], 1);
}

// one block per edge set (grid=4), 256 threads; exclusive prefix over 20000
__global__ __launch_bounds__(256)
void scan_kernel(const int* __restrict__ cnt_all, int* __restrict__ rowptr_all,
                 int* __restrict__ cursor_all) {
    const int S = NN;
    const int CH = 80;  // 256*80 = 20480 >= 20000
    int set = blockIdx.x;
    const int* c = cnt_all + set * S;
    int* rp = rowptr_all + set * S;
    int* cur = cursor_all + set * S;
    int t = threadIdx.x;
    int base = t * CH;
    int sum = 0;
    for (int i = 0; i < CH; ++i) { int idx = base + i; if (idx < S) sum += c[idx]; }
    __shared__ int part[256];
    part[t] = sum;
    __syncthreads();
    for (int off = 1; off < 256; off <<= 1) {
        int v = (t >= off) ? part[t - off] : 0;
        __syncthreads();
        part[t] += v;
        __syncthreads();
    }
    int run = (t == 0) ? 0 : part[t - 1];
    for (int i = 0; i < CH; ++i) {
        int idx = base + i;
        if (idx < S) { rp[idx] = run; cur[idx] = run; run += c[idx]; }
    }
}

__global__ void scatter_kernel(const int* __restrict__ eidx, int* __restrict__ cursor,
                               int* __restrict__ sorted) {
    int e = blockIdx.x * 256 + threadIdx.x;
    if (e >= NE) return;
    int d = eidx[NE + e];
    int p = atomicAdd(&cursor[d], 1);
    sorted[p] = e;
}

// =======================================================================
// message MLP: MFMA 16x16x32 bf16, 64 edges x 128 cols per block, 4 waves
// writes messages (bf16) to Mbuf[E][128] -- no atomics
// =======================================================================
__global__ __launch_bounds__(256, 4)
void msg_kernel(const u16* __restrict__ hb, const float* __restrict__ pos,
                const int* __restrict__ eidx,
                const u16* __restrict__ W1T,   // [128][256] bf16
                const float* __restrict__ W1f, // fp32 [257][128] (k=256 row)
                const float* __restrict__ b1, const float* __restrict__ g1,
                const float* __restrict__ be1,
                const u16* __restrict__ W2T,   // [128][128] bf16
                const float* __restrict__ b2, const float* __restrict__ g2,
                const float* __restrict__ be2,
                u16* __restrict__ Mbuf) {
    __shared__ __align__(16) u16 As[64 * 40];
    __shared__ __align__(16) u16 Ws[128 * 40];
    __shared__ __align__(16) u16 Mt[64 * 136];
    __shared__ float dsh[64];
    __shared__ int dst_sh[64], src_sh[64];

    const int tid = threadIdx.x;
    const int lane = tid & 63;
    const int w = tid >> 6;
    const int r0 = w * 16;
    const int arow = lane & 15;
    const int kg = lane >> 4;
    const int e0 = blockIdx.x * 64;

    if (tid < 64) {
        int e = e0 + tid;
        int s = 0, dn = 0; float dd = 0.f;
        if (e < NE) {
            s = eidx[e];
            dn = eidx[NE + e];
            float dx = pos[dn * 3 + 0] - pos[s * 3 + 0];
            float dy = pos[dn * 3 + 1] - pos[s * 3 + 1];
            float dz = pos[dn * 3 + 2] - pos[s * 3 + 2];
            dd = sqrtf(dx * dx + dy * dy + dz * dz);
        }
        src_sh[tid] = s; dst_sh[tid] = dn; dsh[tid] = dd;
    }
    __syncthreads();

    f32x4 acc[8];
#pragma unroll
    for (int t = 0; t < 8; ++t) acc[t] = (f32x4)0.f;

    const int s_row = tid >> 2, s_k8 = (tid & 3) * 8;
    const int w_col = tid >> 1, w_k16 = (tid & 1) * 16;

    // ---- GEMM1: [64,256] (h[dst]||h[src]) @ W1 ----
    for (int kc = 0; kc < 8; ++kc) {
        const int kb = kc * 32;
        {
            int k = kb + s_k8;
            int node = (k < DD) ? dst_sh[s_row] : src_sh[s_row];
            *(short8*)&As[s_row * 40 + s_k8] =
                *(const short8*)&hb[(size_t)node * DD + (k & (DD - 1))];
            const u16* wsrc = &W1T[(size_t)w_col * 256 + kb + w_k16];
            *(short8*)&Ws[w_col * 40 + w_k16]     = *(const short8*)&wsrc[0];
            *(short8*)&Ws[w_col * 40 + w_k16 + 8] = *(const short8*)&wsrc[8];
        }
        __syncthreads();
        short8 a = *(const short8*)&As[(r0 + arow) * 40 + kg * 8];
#pragma unroll
        for (int t = 0; t < 8; ++t) {
            short8 b = *(const short8*)&Ws[(t * 16 + arow) * 40 + kg * 8];
            acc[t] = __builtin_amdgcn_mfma_f32_16x16x32_bf16(a, b, acc[t], 0, 0, 0);
        }
        __syncthreads();
    }

    // ---- distance col (k=256) + bias + LN1 + SiLU -> Mt (bf16) ----
    {
        float gg[8], ee[8];
#pragma unroll
        for (int t = 0; t < 8; ++t) {
            int col = t * 16 + arow;
            float wd = W1f[256 * DD + col];
            float bb = b1[col];
            gg[t] = g1[col]; ee[t] = be1[col];
#pragma unroll
            for (int r = 0; r < 4; ++r)
                acc[t][r] += dsh[r0 + kg * 4 + r] * wd + bb;
        }
#pragma unroll
        for (int r = 0; r < 4; ++r) {
            float s1 = 0.f, s2 = 0.f;
#pragma unroll
            for (int t = 0; t < 8; ++t) { float v = acc[t][r]; s1 += v; s2 += v * v; }
#pragma unroll
            for (int m = 1; m < 16; m <<= 1) { s1 += __shfl_xor(s1, m); s2 += __shfl_xor(s2, m); }
            float mu = s1 * (1.f / 128.f);
            float var = s2 * (1.f / 128.f) - mu * mu;
            float rs = rsqrtf(var + 1e-5f);
            int row = r0 + kg * 4 + r;
#pragma unroll
            for (int t = 0; t < 8; ++t) {
                float v = (acc[t][r] - mu) * rs * gg[t] + ee[t];
                Mt[row * 136 + t * 16 + arow] = f2b(silu_f(v));
            }
        }
    }
    __syncthreads();

    // ---- GEMM2: M[64,128] @ W2 ----
#pragma unroll
    for (int t = 0; t < 8; ++t) acc[t] = (f32x4)0.f;
    for (int kc = 0; kc < 4; ++kc) {
        const int kb = kc * 32;
        {
            const u16* wsrc = &W2T[(size_t)w_col * 128 + kb + w_k16];
            *(short8*)&Ws[w_col * 40 + w_k16]     = *(const short8*)&wsrc[0];
            *(short8*)&Ws[w_col * 40 + w_k16 + 8] = *(const short8*)&wsrc[8];
        }
        __syncthreads();
        short8 a = *(const short8*)&Mt[(r0 + arow) * 136 + kb + kg * 8];
#pragma unroll
        for (int t = 0; t < 8; ++t) {
            short8 b = *(const short8*)&Ws[(t * 16 + arow) * 40 + kg * 8];
            acc[t] = __builtin_amdgcn_mfma_f32_16x16x32_bf16(a, b, acc[t], 0, 0, 0);
        }
        __syncthreads();
    }

    // ---- bias + LN2 + SiLU -> Mt, then coalesced store to Mbuf ----
    {
        float gg[8], ee[8], bb[8];
#pragma unroll
        for (int t = 0; t < 8; ++t) {
            int col = t * 16 + arow;
            bb[t] = b2[col]; gg[t] = g2[col]; ee[t] = be2[col];
        }
#pragma unroll
        for (int r = 0; r < 4; ++r) {
            int row = r0 + kg * 4 + r;
            float s1 = 0.f, s2 = 0.f;
#pragma unroll
            for (int t = 0; t < 8; ++t) {
                float v = acc[t][r] + bb[t]; acc[t][r] = v; s1 += v; s2 += v * v;
            }
#pragma unroll
            for (int m = 1; m < 16; m <<= 1) { s1 += __shfl_xor(s1, m); s2 += __shfl_xor(s2, m); }
            float mu = s1 * (1.f / 128.f);
            float var = s2 * (1.f / 128.f) - mu * mu;
            float rs = rsqrtf(var + 1e-5f);
#pragma unroll
            for (int t = 0; t < 8; ++t) {
                float v = (acc[t][r] - mu) * rs * gg[t] + ee[t];
                Mt[row * 136 + t * 16 + arow] = f2b(silu_f(v));
            }
        }
    }
    __syncthreads();
    {
        int row = tid >> 2;
        int c0 = (tid & 3) * 32;
        int e = e0 + row;
        if (e < NE) {
            const u16* sp = &Mt[row * 136 + c0];
            u16* dp = &Mbuf[(size_t)e * 128 + c0];
#pragma unroll
            for (int q = 0; q < 4; ++q)
                *(short8*)&dp[q * 8] = *(const short8*)&sp[q * 8];
        }
    }
}

// ============== aggregation: wave per node, 2 cols per lane ==============
__global__ __launch_bounds__(256)
void agg_kernel(const u16* __restrict__ Mbuf, const int* __restrict__ rowptr,
                const int* __restrict__ cnt, const int* __restrict__ sorted,
                u16* __restrict__ aggb) {
    int w = threadIdx.x >> 6, lane = threadIdx.x & 63;
    int n = blockIdx.x * 4 + w;
    if (n >= NN) return;
    int start = rowptr[n], num = cnt[n];
    float a0 = 0.f, a1 = 0.f;
    for (int i = 0; i < num; ++i) {
        int e = sorted[start + i];
        unsigned int v = *(const unsigned int*)&Mbuf[(size_t)e * 128 + lane * 2];
        a0 += b2f((u16)(v & 0xffffu));
        a1 += b2f((u16)(v >> 16));
    }
    unsigned int outv = ((unsigned int)f2b(a1) << 16) | (unsigned int)f2b(a0);
    *(unsigned int*)&aggb[(size_t)n * 128 + lane * 2] = outv;
}

// =======================================================================
// node update MLP: MFMA, 64 nodes x 128 cols per block + residual
// =======================================================================
__global__ __launch_bounds__(256, 4)
void upd_kernel(float* __restrict__ h, u16* __restrict__ hb,
                const u16* __restrict__ aggb,
                const u16* __restrict__ W1T,
                const float* __restrict__ b1, const float* __restrict__ g1,
                const float* __restrict__ be1,
                const u16* __restrict__ W2T,
                const float* __restrict__ b2, const float* __restrict__ g2,
                const float* __restrict__ be2) {
    __shared__ __align__(16) u16 As[64 * 40];
    __shared__ __align__(16) u16 Ws[128 * 40];
    __shared__ __align__(16) u16 Mt[64 * 136];

    const int tid = threadIdx.x;
    const int lane = tid & 63;
    const int w = tid >> 6;
    const int r0 = w * 16;
    const int arow = lane & 15;
    const int kg = lane >> 4;
    const int n0 = blockIdx.x * 64;

    f32x4 acc[8];
#pragma unroll
    for (int t = 0; t < 8; ++t) acc[t] = (f32x4)0.f;

    const int s_row = tid >> 2, s_k8 = (tid & 3) * 8;
    const int w_col = tid >> 1, w_k16 = (tid & 1) * 16;

    // ---- GEMM1: [64,256] (h || agg) @ W1 ----
    for (int kc = 0; kc < 8; ++kc) {
        const int kb = kc * 32;
        {
            int k = kb + s_k8;
            int n = n0 + s_row;
            int nn = (n < NN) ? n : 0;
            const u16* srcb = (k < DD) ? &hb[(size_t)nn * DD + k]
                                       : &aggb[(size_t)nn * DD + (k - DD)];
            *(short8*)&As[s_row * 40 + s_k8] = *(const short8*)srcb;
            const u16* wsrc = &W1T[(size_t)w_col * 256 + kb + w_k16];
            *(short8*)&Ws[w_col * 40 + w_k16]     = *(const short8*)&wsrc[0];
            *(short8*)&Ws[w_col * 40 + w_k16 + 8] = *(const short8*)&wsrc[8];
        }
        __syncthreads();
        short8 a = *(const short8*)&As[(r0 + arow) * 40 + kg * 8];
#pragma unroll
        for (int t = 0; t < 8; ++t) {
            short8 b = *(const short8*)&Ws[(t * 16 + arow) * 40 + kg * 8];
            acc[t] = __builtin_amdgcn_mfma_f32_16x16x32_bf16(a, b, acc[t], 0, 0, 0);
        }
        __syncthreads();
    }

    // ---- bias + LN1 + SiLU -> Mt ----
    {
        float gg[8], ee[8], bb[8];
#pragma unroll
        for (int t = 0; t < 8; ++t) {
            int col = t * 16 + arow;
            bb[t] = b1[col]; gg[t] = g1[col]; ee[t] = be1[col];
        }
#pragma unroll
        for (int r = 0; r < 4; ++r) {
            float s1 = 0.f, s2 = 0.f;
#pragma unroll
            for (int t = 0; t < 8; ++t) {
                float v = acc[t][r] + bb[t]; acc[t][r] = v; s1 += v; s2 += v * v;
            }
#pragma unroll
            for (int m = 1; m < 16; m <<= 1) { s1 += __shfl_xor(s1, m); s2 += __shfl_xor(s2, m); }
            float mu = s1 * (1.f / 128.f);
            float var = s2 * (1.f / 128.f) - mu * mu;
            float rs = rsqrtf(var + 1e-5f);
            int row = r0 + kg * 4 + r;
#pragma unroll
            for (int t = 0; t < 8; ++t) {
                float v = (acc[t][r] - mu) * rs * gg[t] + ee[t];
                Mt[row * 136 + t * 16 + arow] = f2b(silu_f(v));
            }
        }
    }
    __syncthreads();

    // ---- GEMM2 ----
#pragma unroll
    for (int t = 0; t < 8; ++t) acc[t] = (f32x4)0.f;
    for (int kc = 0; kc < 4; ++kc) {
        const int kb = kc * 32;
        {
            const u16* wsrc = &W2T[(size_t)w_col * 128 + kb + w_k16];
            *(short8*)&Ws[w_col * 40 + w_k16]     = *(const short8*)&wsrc[0];
            *(short8*)&Ws[w_col * 40 + w_k16 + 8] = *(const short8*)&wsrc[8];
        }
        __syncthreads();
        short8 a = *(const short8*)&Mt[(r0 + arow) * 136 + kb + kg * 8];
#pragma unroll
        for (int t = 0; t < 8; ++t) {
            short8 b = *(const short8*)&Ws[(t * 16 + arow) * 40 + kg * 8];
            acc[t] = __builtin_amdgcn_mfma_f32_16x16x32_bf16(a, b, acc[t], 0, 0, 0);
        }
        __syncthreads();
    }

    // ---- bias + LN2 + SiLU + residual (h fp32 + hb bf16) ----
    {
        float gg[8], ee[8], bb[8];
#pragma unroll
        for (int t = 0; t < 8; ++t) {
            int col = t * 16 + arow;
            bb[t] = b2[col]; gg[t] = g2[col]; ee[t] = be2[col];
        }
#pragma unroll
        for (int r = 0; r < 4; ++r) {
            int row = r0 + kg * 4 + r;
            float s1 = 0.f, s2 = 0.f;
#pragma unroll
            for (int t = 0; t < 8; ++t) {
                float v = acc[t][r] + bb[t]; acc[t][r] = v; s1 += v; s2 += v * v;
            }
#pragma unroll
            for (int m = 1; m < 16; m <<= 1) { s1 += __shfl_xor(s1, m); s2 += __shfl_xor(s2, m); }
            float mu = s1 * (1.f / 128.f);
            float var = s2 * (1.f / 128.f) - mu * mu;
            float rs = rsqrtf(var + 1e-5f);
            int n = n0 + row;
            if (n < NN) {
                float* hp = &h[(size_t)n * DD];
                u16* hbp = &hb[(size_t)n * DD];
#pragma unroll
                for (int t = 0; t < 8; ++t) {
                    int col = t * 16 + arow;
                    float v = (acc[t][r] - mu) * rs * gg[t] + ee[t];
                    float nh = hp[col] + silu_f(v);
                    hp[col] = nh;
                    hbp[col] = f2b(nh);
                }
            }
        }
    }
}

// ---------------- global add pool ----------------
__global__ void pool_kernel(const float* __restrict__ h, const int* __restrict__ batch,
                            float* __restrict__ pooled) {
    int gid = blockIdx.x * 256 + threadIdx.x;
    if (gid >= NN * DD) return;
    int n = gid >> 7, c = gid & 127;
    atomicAdd(&pooled[batch[n] * DD + c], h[gid]);
}

// ---------------- prediction head ----------------
__global__ __launch_bounds__(128)
void pred_kernel(const float* __restrict__ pooled,
                 const float* __restrict__ W1, const float* __restrict__ b1,
                 const float* __restrict__ W2, const float* __restrict__ b2,
                 float* __restrict__ out) {
    __shared__ float prow[128];
    __shared__ float wsum[2];
    int g = blockIdx.x, c = threadIdx.x;
    prow[c] = pooled[g * DD + c];
    __syncthreads();
    float t = b1[c];
#pragma unroll 8
    for (int k = 0; k < DD; ++k) t += prow[k] * W1[k * DD + c];
    t = fmaxf(t, 0.f) * W2[c];
#pragma unroll
    for (int m = 32; m >= 1; m >>= 1) t += __shfl_down(t, m);
    if ((c & 63) == 0) wsum[c >> 6] = t;
    __syncthreads();
    if (c == 0) out[g] = wsum[0] + wsum[1] + b2[0];
}

extern "C" void kernel_launch(void* const* d_in, const int* in_sizes, int n_in,
                              void* d_out, int out_size, void* d_ws, size_t ws_size,
                              hipStream_t stream) {
    const float* x    = (const float*)d_in[0];
    const float* pos  = (const float*)d_in[1];
    const int* eidx[4] = {(const int*)d_in[2], (const int*)d_in[3],
                          (const int*)d_in[4], (const int*)d_in[5]};
    const int* batch  = (const int*)d_in[6];
    const float* emb_W  = (const float*)d_in[7];
    const float* emb_b  = (const float*)d_in[8];
    const float* msg_W1 = (const float*)d_in[9];
    const float* msg_b1 = (const float*)d_in[10];
    const float* msg_g1 = (const float*)d_in[11];
    const float* msg_be1= (const float*)d_in[12];
    const float* msg_W2 = (const float*)d_in[13];
    const float* msg_b2 = (const float*)d_in[14];
    const float* msg_g2 = (const float*)d_in[15];
    const float* msg_be2= (const float*)d_in[16];
    const float* upd_W1 = (const float*)d_in[17];
    const float* upd_b1 = (const float*)d_in[18];
    const float* upd_g1 = (const float*)d_in[19];
    const float* upd_be1= (const float*)d_in[20];
    const float* upd_W2 = (const float*)d_in[21];
    const float* upd_b2 = (const float*)d_in[22];
    const float* upd_g2 = (const float*)d_in[23];
    const float* upd_be2= (const float*)d_in[24];
    const float* pred_W1= (const float*)d_in[25];
    const float* pred_b1= (const float*)d_in[26];
    const float* pred_W2= (const float*)d_in[27];
    const float* pred_b2= (const float*)d_in[28];
    float* out = (float*)d_out;

    // ---- workspace layout ----
    float* h      = (float*)d_ws;                    // NN*DD f32
    float* pooled = h + (size_t)NN * DD;             // NG*DD f32
    int* cnt      = (int*)(pooled + NG * DD);        // 4*NN
    int* rowptr   = cnt + 4 * NN;                    // 4*NN
    int* cursor   = rowptr + 4 * NN;                 // 4*NN
    int* sorted   = cursor + 4 * NN;                 // 4*NE
    u16* hb       = (u16*)(sorted + 4 * NE);         // NN*DD
    u16* aggb     = hb + (size_t)NN * DD;            // NN*DD
    u16* Mbuf     = aggb + (size_t)NN * DD;          // NE*DD
    u16* msgW1T   = Mbuf + (size_t)NE * DD;
    u16* msgW2T   = msgW1T + (size_t)NL * 128 * 256;
    u16* updW1T   = msgW2T + (size_t)NL * 128 * 128;
    u16* updW2T   = updW1T + (size_t)NL * 128 * 256;

    // ---- weight prep ----
    int t1 = NL * 128 * 256, t2 = NL * 128 * 128;
    wprep_kernel<<<(t1 + 255) / 256, 256, 0, stream>>>(msg_W1, msgW1T, 257, 256);
    wprep_kernel<<<(t2 + 255) / 256, 256, 0, stream>>>(msg_W2, msgW2T, 128, 128);
    wprep_kernel<<<(t1 + 255) / 256, 256, 0, stream>>>(upd_W1, updW1T, 256, 256);
    wprep_kernel<<<(t2 + 255) / 256, 256, 0, stream>>>(upd_W2, updW2T, 128, 128);

    // ---- CSR build for the 4 edge sets ----
    hipMemsetAsync(cnt, 0, 4 * NN * sizeof(int), stream);
    for (int s = 0; s < 4; ++s)
        hist_kernel<<<(NE + 255) / 256, 256, 0, stream>>>(eidx[s], cnt + s * NN);
    scan_kernel<<<4, 256, 0, stream>>>(cnt, rowptr, cursor);
    for (int s = 0; s < 4; ++s)
        scatter_kernel<<<(NE + 255) / 256, 256, 0, stream>>>(eidx[s], cursor + s * NN,
                                                             sorted + (size_t)s * NE);

    embed_kernel<<<(NN * DD + 255) / 256, 256, 0, stream>>>(x, emb_W, emb_b, h, hb);

    for (int li = 0; li < NL; ++li) {
        int gi = li & 3;
        msg_kernel<<<(NE + 63) / 64, 256, 0, stream>>>(
            hb, pos, eidx[gi],
            msgW1T + (size_t)li * 128 * 256,
            msg_W1 + (size_t)li * 257 * DD,
            msg_b1 + li * DD, msg_g1 + li * DD, msg_be1 + li * DD,
            msgW2T + (size_t)li * 128 * 128,
            msg_b2 + li * DD, msg_g2 + li * DD, msg_be2 + li * DD,
            Mbuf);
        agg_kernel<<<(NN + 3) / 4, 256, 0, stream>>>(
            Mbuf, rowptr + gi * NN, cnt + gi * NN, sorted + (size_t)gi * NE, aggb);
        upd_kernel<<<(NN + 63) / 64, 256, 0, stream>>>(
            h, hb, aggb,
            updW1T + (size_t)li * 128 * 256,
            upd_b1 + li * DD, upd_g1 + li * DD, upd_be1 + li * DD,
            updW2T + (size_t)li * 128 * 128,
            upd_b2 + li * DD, upd_g2 + li * DD, upd_be2 + li * DD);
    }

    hipMemsetAsync(pooled, 0, NG * DD * sizeof(float), stream);
    pool_kernel<<<(NN * DD + 255) / 256, 256, 0, stream>>>(h, batch, pooled);
    pred_kernel<<<NG, 128, 0, stream>>>(pooled, pred_W1, pred_b1, pred_W2, pred_b2, out);
}